// Round 1
// baseline (61.106 us; speedup 1.0000x reference)
//
#include <hip/hip_runtime.h>

// Chamfer distance, B=16, N=M=4096, fp32.
// Strategy: dist(q,p) = |q|^2 + min_p(|p|^2 - 2 q.p)  -> 3 fma + 1 min per pair.
// Kernel 1: partial mins over target chunks (both directions in one launch).
// Kernel 2: reduce chunks -> mean(dist1) + mean(dist2) scalar.

#define BATCH 16
#define NPTS  4096
#define BLK   256   // threads per block
#define QPT   8     // queries per thread  -> 2048 queries per block
#define QTILE (BLK * QPT)
#define NQT   (NPTS / QTILE)   // 2 query tiles per batch
#define TCH   512   // targets per chunk (staged in LDS)
#define NTC   (NPTS / TCH)     // 8 target chunks
#define NQ_TOTAL (BATCH * NPTS)  // 65536 queries per direction

__global__ __launch_bounds__(BLK) void chamfer_partial_kernel(
    const float* __restrict__ xyz1, const float* __restrict__ xyz2,
    float* __restrict__ ws)
{
    const int b   = blockIdx.x;         // batch
    const int qt  = blockIdx.y;         // query tile (0..NQT-1)
    const int zz  = blockIdx.z;         // tc (0..NTC-1) | dir<<3
    const int tc  = zz & (NTC - 1);
    const int dir = zz >> 3;

    const float* __restrict__ qp = dir ? xyz2 : xyz1;
    const float* __restrict__ tp = dir ? xyz1 : xyz2;

    __shared__ float4 tgt[TCH];

    // Stage target chunk into LDS as [x, y, z, |p|^2]
    const float* tbase = tp + ((size_t)b * NPTS + (size_t)tc * TCH) * 3;
    for (int i = threadIdx.x; i < TCH; i += BLK) {
        float x = tbase[i * 3 + 0];
        float y = tbase[i * 3 + 1];
        float z = tbase[i * 3 + 2];
        tgt[i] = make_float4(x, y, z, fmaf(x, x, fmaf(y, y, z * z)));
    }
    __syncthreads();

    // Load QPT query points into registers; precompute -2q and |q|^2.
    float m2x[QPT], m2y[QPT], m2z[QPT], qsq[QPT], acc[QPT];
    const float* qbase = qp + ((size_t)b * NPTS + (size_t)qt * QTILE) * 3;
    #pragma unroll
    for (int i = 0; i < QPT; ++i) {
        int qi = i * BLK + (int)threadIdx.x;
        float x = qbase[qi * 3 + 0];
        float y = qbase[qi * 3 + 1];
        float z = qbase[qi * 3 + 2];
        m2x[i] = -2.0f * x;
        m2y[i] = -2.0f * y;
        m2z[i] = -2.0f * z;
        qsq[i] = fmaf(x, x, fmaf(y, y, z * z));
        acc[i] = 1e30f;
    }

    // Main loop: broadcast ds_read_b128 per target, 8 independent fma chains.
    #pragma unroll 4
    for (int t = 0; t < TCH; ++t) {
        float4 p = tgt[t];
        #pragma unroll
        for (int i = 0; i < QPT; ++i) {
            float d = fmaf(m2x[i], p.x, fmaf(m2y[i], p.y, fmaf(m2z[i], p.z, p.w)));
            acc[i] = fminf(acc[i], d);
        }
    }

    // Write partial mins: ws[(dir*NTC + tc)][global_query]
    float* w = ws + ((size_t)(dir * NTC + tc)) * NQ_TOTAL;
    #pragma unroll
    for (int i = 0; i < QPT; ++i) {
        int q = b * NPTS + qt * QTILE + i * BLK + (int)threadIdx.x;
        float d = acc[i] + qsq[i];
        w[q] = d > 0.0f ? d : 0.0f;   // == min over clamped pair distances
    }
}

__global__ __launch_bounds__(BLK) void chamfer_reduce_kernel(
    const float* __restrict__ ws, float* __restrict__ out)
{
    // 2 * 65536 query-min values; j = dir*65536 + q
    const int j   = blockIdx.x * BLK + (int)threadIdx.x;   // grid covers exactly 131072
    const int dir = j >> 16;
    const int q   = j & (NQ_TOTAL - 1);

    const float* w = ws + (size_t)dir * NTC * NQ_TOTAL + q;
    float m = w[0];
    #pragma unroll
    for (int tc = 1; tc < NTC; ++tc) m = fminf(m, w[(size_t)tc * NQ_TOTAL]);

    float v = m * (1.0f / (float)NQ_TOTAL);   // mean contribution (N == M)

    // wave64 reduce
    #pragma unroll
    for (int off = 32; off >= 1; off >>= 1)
        v += __shfl_down(v, off, 64);

    __shared__ float wsum[BLK / 64];
    const int lane = (int)threadIdx.x & 63;
    const int wid  = (int)threadIdx.x >> 6;
    if (lane == 0) wsum[wid] = v;
    __syncthreads();
    if (threadIdx.x == 0) {
        float s = wsum[0] + wsum[1] + wsum[2] + wsum[3];
        atomicAdd(out, s);
    }
}

extern "C" void kernel_launch(void* const* d_in, const int* in_sizes, int n_in,
                              void* d_out, int out_size, void* d_ws, size_t ws_size,
                              hipStream_t stream) {
    const float* xyz1 = (const float*)d_in[0];
    const float* xyz2 = (const float*)d_in[1];
    float* out = (float*)d_out;
    float* ws  = (float*)d_ws;

    // zero the scalar accumulator (graph-capturable)
    hipMemsetAsync(out, 0, sizeof(float), stream);

    dim3 grid1(BATCH, NQT, NTC * 2);   // 16 x 2 x 16 = 512 blocks
    chamfer_partial_kernel<<<grid1, BLK, 0, stream>>>(xyz1, xyz2, ws);

    dim3 grid2((2 * NQ_TOTAL) / BLK);  // 512 blocks
    chamfer_reduce_kernel<<<grid2, BLK, 0, stream>>>(ws, out);
}

// Round 2
// 59.062 us; speedup vs baseline: 1.0346x; 1.0346x over previous
//
#include <hip/hip_runtime.h>

// Chamfer distance, B=16, N=M=4096, fp32.
// dist(q,p) = |q|^2 + min_p(|p|^2 - 2 q.p)  -> 3 fma + 1 min per pair.
// R2: 1024 blocks (4 waves/SIMD, was 2) + explicit LDS->reg prefetch pipeline.

#define BATCH 16
#define NPTS  4096
#define BLK   256   // threads per block
#define QPT   4     // queries per thread  -> 1024 queries per block
#define QTILE (BLK * QPT)
#define NQT   (NPTS / QTILE)   // 4 query tiles per batch
#define TCH   512   // targets per chunk (staged in LDS)
#define NTC   (NPTS / TCH)     // 8 target chunks
#define NQ_TOTAL (BATCH * NPTS)  // 65536 queries per direction

__global__ __launch_bounds__(BLK) void chamfer_partial_kernel(
    const float* __restrict__ xyz1, const float* __restrict__ xyz2,
    float* __restrict__ ws)
{
    const int b   = blockIdx.x;         // batch
    const int qt  = blockIdx.y;         // query tile (0..NQT-1)
    const int zz  = blockIdx.z;         // tc (0..NTC-1) | dir<<3
    const int tc  = zz & (NTC - 1);
    const int dir = zz >> 3;

    const float* __restrict__ qp = dir ? xyz2 : xyz1;
    const float* __restrict__ tp = dir ? xyz1 : xyz2;

    __shared__ float4 tgt[TCH + 1];   // +1 pad so the prefetch never branches

    // Stage target chunk into LDS as [x, y, z, |p|^2]
    const float* tbase = tp + ((size_t)b * NPTS + (size_t)tc * TCH) * 3;
    for (int i = threadIdx.x; i < TCH; i += BLK) {
        float x = tbase[i * 3 + 0];
        float y = tbase[i * 3 + 1];
        float z = tbase[i * 3 + 2];
        tgt[i] = make_float4(x, y, z, fmaf(x, x, fmaf(y, y, z * z)));
    }
    __syncthreads();

    // Load QPT query points into registers; precompute -2q and |q|^2.
    float m2x[QPT], m2y[QPT], m2z[QPT], qsq[QPT], acc[QPT];
    const float* qbase = qp + ((size_t)b * NPTS + (size_t)qt * QTILE) * 3;
    #pragma unroll
    for (int i = 0; i < QPT; ++i) {
        int qi = i * BLK + (int)threadIdx.x;
        float x = qbase[qi * 3 + 0];
        float y = qbase[qi * 3 + 1];
        float z = qbase[qi * 3 + 2];
        m2x[i] = -2.0f * x;
        m2y[i] = -2.0f * y;
        m2z[i] = -2.0f * z;
        qsq[i] = fmaf(x, x, fmaf(y, y, z * z));
        acc[i] = 1e30f;
    }

    // Main loop: rotating prefetch -> ds_read latency hides under 16 VALU ops.
    float4 p = tgt[0];
    #pragma unroll 8
    for (int t = 0; t < TCH; ++t) {
        float4 pn = tgt[t + 1];
        #pragma unroll
        for (int i = 0; i < QPT; ++i) {
            float d = fmaf(m2x[i], p.x, fmaf(m2y[i], p.y, fmaf(m2z[i], p.z, p.w)));
            acc[i] = fminf(acc[i], d);
        }
        p = pn;
    }

    // Write partial mins: ws[(dir*NTC + tc)][global_query]
    float* w = ws + ((size_t)(dir * NTC + tc)) * NQ_TOTAL;
    #pragma unroll
    for (int i = 0; i < QPT; ++i) {
        int q = b * NPTS + qt * QTILE + i * BLK + (int)threadIdx.x;
        float d = acc[i] + qsq[i];
        w[q] = d > 0.0f ? d : 0.0f;   // == min over clamped pair distances
    }
}

__global__ __launch_bounds__(BLK) void chamfer_reduce_kernel(
    const float* __restrict__ ws, float* __restrict__ out)
{
    // 2 * 65536 query-min values; j = dir*65536 + q
    const int j   = blockIdx.x * BLK + (int)threadIdx.x;   // grid covers exactly 131072
    const int dir = j >> 16;
    const int q   = j & (NQ_TOTAL - 1);

    const float* w = ws + (size_t)dir * NTC * NQ_TOTAL + q;
    float m = w[0];
    #pragma unroll
    for (int tc = 1; tc < NTC; ++tc) m = fminf(m, w[(size_t)tc * NQ_TOTAL]);

    float v = m * (1.0f / (float)NQ_TOTAL);   // mean contribution (N == M)

    // wave64 reduce
    #pragma unroll
    for (int off = 32; off >= 1; off >>= 1)
        v += __shfl_down(v, off, 64);

    __shared__ float wsum[BLK / 64];
    const int lane = (int)threadIdx.x & 63;
    const int wid  = (int)threadIdx.x >> 6;
    if (lane == 0) wsum[wid] = v;
    __syncthreads();
    if (threadIdx.x == 0) {
        float s = wsum[0] + wsum[1] + wsum[2] + wsum[3];
        atomicAdd(out, s);
    }
}

extern "C" void kernel_launch(void* const* d_in, const int* in_sizes, int n_in,
                              void* d_out, int out_size, void* d_ws, size_t ws_size,
                              hipStream_t stream) {
    const float* xyz1 = (const float*)d_in[0];
    const float* xyz2 = (const float*)d_in[1];
    float* out = (float*)d_out;
    float* ws  = (float*)d_ws;

    // zero the scalar accumulator (graph-capturable)
    hipMemsetAsync(out, 0, sizeof(float), stream);

    dim3 grid1(BATCH, NQT, NTC * 2);   // 16 x 4 x 16 = 1024 blocks
    chamfer_partial_kernel<<<grid1, BLK, 0, stream>>>(xyz1, xyz2, ws);

    dim3 grid2((2 * NQ_TOTAL) / BLK);  // 512 blocks
    chamfer_reduce_kernel<<<grid2, BLK, 0, stream>>>(ws, out);
}